// Round 1
// baseline (666.339 us; speedup 1.0000x reference)
//
#include <hip/hip_runtime.h>
#include <math.h>

// Problem dims (fixed)
#define NB 16
#define NV 12
#define NROWS 192          // NB*NV
#define DRAW 200704
#define KOUT 256
#define DFEAT 1024
#define NG 8
#define NCLS 40

// K1 GEMM decomposition
#define NCHUNK 256
#define KC 784             // 200704 / 256
#define DSTEP 64
#define NSTAGE 13          // 12*64 + 16 = 784 (zero-padded remainder)

// workspace layout (bytes)
#define WS_P      0                         // [192][256] f32 (atomic fallback)
#define WS_SCORE  196608                    // [192] f32
#define WS_COEFF  197632                    // [192] f32
#define WS_DESC   198656                    // [16][1024] f32
#define WS_Z1     264192                    // [16][512] f32
#define WS_Z2     296960                    // [16][256] f32
#define WS_PART   524288                    // [256][192][256] f32
#define WS_NEED   (WS_PART + (size_t)NCHUNK*NROWS*KOUT*4)

__global__ __launch_bounds__(256) void k0_zero(float* __restrict__ P) {
    P[blockIdx.x * 256 + threadIdx.x] = 0.f;
}

// Main GEMM: P[row][col] = sum_d raw[row][d] * W1[d][col], K-chunked over blocks.
// Block = 512 threads: col = t&255, row-half = t>>8 (96 rows each) -> acc[96].
// A-tile staged in LDS (dd-major [64][192]); A reads are wave-broadcast (all
// lanes same address) so layout bank conflicts only hit the staging writes.
__global__ __launch_bounds__(512)
void k1_gemm(const float* __restrict__ raw, const float* __restrict__ W1,
             const int* __restrict__ vnum, float* __restrict__ outP, int atomicMode)
{
    __shared__ float As[DSTEP * NROWS];
    __shared__ int vns[NB];
    const int t = threadIdx.x;
    const int c = blockIdx.x;
    const int d0 = c * KC;
    const int dend = d0 + KC;
    if (t < NB) vns[t] = vnum[t];
    const int col = t & 255;
    const int rbase = (t >> 8) * 96;
    float acc[96];
#pragma unroll
    for (int r = 0; r < 96; ++r) acc[r] = 0.f;
    __syncthreads();

    for (int s = 0; s < NSTAGE; ++s) {
        const int dbase = d0 + s * DSTEP;
        // stage A: coalesced global reads (row-major i), skip inactive views
        for (int i = t; i < NROWS * DSTEP; i += 512) {
            int row = i >> 6;
            int dd = i & 63;
            int d = dbase + dd;
            float v = 0.f;
            if (d < dend && (row % NV) < vns[row / NV])
                v = raw[(size_t)row * DRAW + d];
            As[dd * NROWS + row] = v;
        }
        __syncthreads();
#pragma unroll 1
        for (int g = 0; g < 8; ++g) {
            float w[8];
#pragma unroll
            for (int q = 0; q < 8; ++q) {
                int d = dbase + g * 8 + q;
                w[q] = (d < dend) ? W1[(size_t)d * KOUT + col] : 0.f;
            }
#pragma unroll
            for (int q = 0; q < 8; ++q) {
                const float4* a4 =
                    reinterpret_cast<const float4*>(&As[(g * 8 + q) * NROWS + rbase]);
#pragma unroll
                for (int r4 = 0; r4 < 24; ++r4) {
                    float4 a = a4[r4];
                    acc[4 * r4 + 0] = fmaf(a.x, w[q], acc[4 * r4 + 0]);
                    acc[4 * r4 + 1] = fmaf(a.y, w[q], acc[4 * r4 + 1]);
                    acc[4 * r4 + 2] = fmaf(a.z, w[q], acc[4 * r4 + 2]);
                    acc[4 * r4 + 3] = fmaf(a.w, w[q], acc[4 * r4 + 3]);
                }
            }
        }
        __syncthreads();
    }

    if (atomicMode) {
#pragma unroll
        for (int r = 0; r < 96; ++r)
            atomicAdd(&outP[(rbase + r) * KOUT + col], acc[r]);
    } else {
#pragma unroll
        for (int r = 0; r < 96; ++r)
            outP[(size_t)c * NROWS * KOUT + (rbase + r) * KOUT + col] = acc[r];
    }
}

// Reduce partials + score head: h=relu(P+b1); sraw=relu(h.W2+b2);
// score = sigmoid(tanh(|sraw|))
__global__ __launch_bounds__(256)
void k2_score(const float* __restrict__ part, int nchunk,
              const float* __restrict__ b1, const float* __restrict__ W2,
              const float* __restrict__ b2, float* __restrict__ score)
{
    const int row = blockIdx.x;
    const int t = threadIdx.x;
    float s = 0.f;
    for (int cI = 0; cI < nchunk; ++cI)
        s += part[(size_t)cI * NROWS * KOUT + row * KOUT + t];
    float h = fmaxf(s + b1[t], 0.f);
    float val = h * W2[t];
    for (int o = 32; o > 0; o >>= 1) val += __shfl_down(val, o, 64);
    __shared__ float red[4];
    if ((t & 63) == 0) red[t >> 6] = val;
    __syncthreads();
    if (t == 0) {
        float sm = red[0] + red[1] + red[2] + red[3];
        float sraw = fmaxf(sm + b2[0], 0.f);
        float sc = 1.f / (1.f + expf(-tanhf(fabsf(sraw))));
        score[row] = sc;
    }
}

// Per-sample binning: counts, ceil-weights, per-view fusion coefficient
// coeff[v] = weight[bin(v)] / (cnt[bin(v)] * sum_g weight[g])  (active views)
__global__ __launch_bounds__(64)
void k3_bins(const float* __restrict__ score, const int* __restrict__ vnum,
             float* __restrict__ coeff)
{
    const int n = blockIdx.x;
    const int v = threadIdx.x;
    __shared__ int cnt[NG];
    __shared__ float wsum[NG], wt[NG], wtot;
    if (v < NG) { cnt[v] = 0; wsum[v] = 0.f; }
    __syncthreads();
    const int vn = vnum[n];
    const bool act = (v < NV) && (v < vn);
    float sc = 0.f;
    int b = 0;
    if (act) {
        sc = score[n * NV + v];
        b = (int)floorf(sc * 8.f);
        b = b < 0 ? 0 : (b > 7 ? 7 : b);
        atomicAdd(&cnt[b], 1);
    }
    __syncthreads();
    if (act) atomicAdd(&wsum[b], ceilf(sc * (float)cnt[b]));
    __syncthreads();
    if (v < NG) wt[v] = (cnt[v] > 0) ? wsum[v] / (float)cnt[v] : 0.f;
    __syncthreads();
    if (v == 0) {
        float s = 0.f;
        for (int g = 0; g < NG; ++g) s += wt[g];
        wtot = s;
    }
    __syncthreads();
    if (v < NV)
        coeff[n * NV + v] = act ? wt[b] / ((float)cnt[b] * wtot) : 0.f;
}

// desc[n][d] = sum_v coeff[n][v] * final_views[n][v][d]
__global__ __launch_bounds__(256)
void k4_desc(const float* __restrict__ fv, const float* __restrict__ coeff,
             float* __restrict__ desc)
{
    const int n = blockIdx.y;
    const int d = blockIdx.x * 256 + threadIdx.x;
    float a = 0.f;
#pragma unroll
    for (int v = 0; v < NV; ++v)
        a = fmaf(coeff[n * NV + v], fv[((size_t)n * NV + v) * DFEAT + d], a);
    desc[n * DFEAT + d] = a;
}

// z1 = relu(desc @ Wf1 + bf1)  [16,512]
__global__ __launch_bounds__(256)
void k5a(const float* __restrict__ desc, const float* __restrict__ Wf1,
         const float* __restrict__ bf1, float* __restrict__ z1)
{
    const int j = blockIdx.x * 256 + threadIdx.x;   // 0..511
    const int n0 = blockIdx.y * 2;
    float a0 = 0.f, a1 = 0.f;
    for (int d = 0; d < DFEAT; ++d) {
        float w = Wf1[d * 512 + j];
        a0 = fmaf(desc[n0 * DFEAT + d], w, a0);
        a1 = fmaf(desc[(n0 + 1) * DFEAT + d], w, a1);
    }
    z1[n0 * 512 + j] = fmaxf(a0 + bf1[j], 0.f);
    z1[(n0 + 1) * 512 + j] = fmaxf(a1 + bf1[j], 0.f);
}

// z2 = relu(z1 @ Wf2 + bf2)  [16,256]
__global__ __launch_bounds__(256)
void k5b(const float* __restrict__ z1, const float* __restrict__ Wf2,
         const float* __restrict__ bf2, float* __restrict__ z2)
{
    const int j = threadIdx.x;
    const int n0 = blockIdx.x * 2;
    float a0 = 0.f, a1 = 0.f;
    for (int d = 0; d < 512; ++d) {
        float w = Wf2[d * 256 + j];
        a0 = fmaf(z1[n0 * 512 + d], w, a0);
        a1 = fmaf(z1[(n0 + 1) * 512 + d], w, a1);
    }
    z2[n0 * 256 + j] = fmaxf(a0 + bf2[j], 0.f);
    z2[(n0 + 1) * 256 + j] = fmaxf(a1 + bf2[j], 0.f);
}

// out = z2 @ Wl + bl  [16,40]
__global__ __launch_bounds__(640)
void k5c(const float* __restrict__ z2, const float* __restrict__ Wl,
         const float* __restrict__ bl, float* __restrict__ out)
{
    const int t = threadIdx.x;
    const int n = t / NCLS;
    const int j = t % NCLS;
    float a = 0.f;
    for (int d = 0; d < 256; ++d)
        a = fmaf(z2[n * 256 + d], Wl[d * NCLS + j], a);
    out[t] = a + bl[j];
}

extern "C" void kernel_launch(void* const* d_in, const int* in_sizes, int n_in,
                              void* d_out, int out_size, void* d_ws, size_t ws_size,
                              hipStream_t stream)
{
    const float* raw  = (const float*)d_in[0];
    const float* fv   = (const float*)d_in[1];
    const int*   vnum = (const int*)d_in[2];
    const float* W1   = (const float*)d_in[3];
    const float* b1   = (const float*)d_in[4];
    const float* W2   = (const float*)d_in[5];
    const float* b2   = (const float*)d_in[6];
    const float* Wf1  = (const float*)d_in[7];
    const float* bf1  = (const float*)d_in[8];
    const float* Wf2  = (const float*)d_in[9];
    const float* bf2  = (const float*)d_in[10];
    const float* Wl   = (const float*)d_in[11];
    const float* bl   = (const float*)d_in[12];
    float* out = (float*)d_out;
    char* ws = (char*)d_ws;
    float* P     = (float*)(ws + WS_P);
    float* score = (float*)(ws + WS_SCORE);
    float* coeff = (float*)(ws + WS_COEFF);
    float* desc  = (float*)(ws + WS_DESC);
    float* z1    = (float*)(ws + WS_Z1);
    float* z2    = (float*)(ws + WS_Z2);
    float* part  = (float*)(ws + WS_PART);

    const bool twophase = (ws_size >= WS_NEED);
    if (twophase) {
        k1_gemm<<<NCHUNK, 512, 0, stream>>>(raw, W1, vnum, part, 0);
        k2_score<<<NROWS, 256, 0, stream>>>(part, NCHUNK, b1, W2, b2, score);
    } else {
        k0_zero<<<NROWS, 256, 0, stream>>>(P);
        k1_gemm<<<NCHUNK, 512, 0, stream>>>(raw, W1, vnum, P, 1);
        k2_score<<<NROWS, 256, 0, stream>>>(P, 1, b1, W2, b2, score);
    }
    k3_bins<<<NB, 64, 0, stream>>>(score, vnum, coeff);
    k4_desc<<<dim3(4, NB), 256, 0, stream>>>(fv, coeff, desc);
    k5a<<<dim3(2, 8), 256, 0, stream>>>(desc, Wf1, bf1, z1);
    k5b<<<8, 256, 0, stream>>>(z1, Wf2, bf2, z2);
    k5c<<<1, 640, 0, stream>>>(z2, Wl, bl, out);
}

// Round 2
// 253.657 us; speedup vs baseline: 2.6269x; 2.6269x over previous
//
#include <hip/hip_runtime.h>
#include <math.h>

// Problem dims (fixed)
#define NB 16
#define NV 12
#define NROWS 192          // NB*NV
#define DRAW 200704
#define KOUT 256
#define DFEAT 1024
#define NG 8
#define NCLS 40

// K1 GEMM decomposition: 256 blocks x K-chunk 784 (25 steps of 32, last half-padded)
#define NCHUNK 256
#define KC 784
#define KSTEPS 25

// LDS layout (bytes): A tiles 12 x 2048 (1KB hi + 1KB lo, fragment-linear),
// B tiles 16 x 2048. Total 57344.
#define ABASE 0
#define BBASE 24576

// workspace layout (bytes)
#define WS_P      0                         // [192][256] f32 (atomic fallback)
#define WS_SCORE  196608                    // [192] f32
#define WS_COEFF  197632                    // [192] f32
#define WS_DESC   198656                    // [16][1024] f32
#define WS_Z1     264192                    // [16][512] f32
#define WS_Z2     296960                    // [16][256] f32
#define WS_PART   524288                    // [256][192][256] f32
#define WS_NEED   (WS_PART + (size_t)NCHUNK*NROWS*KOUT*4)

typedef __attribute__((ext_vector_type(8))) short short8;
typedef __attribute__((ext_vector_type(4))) float f32x4;

__global__ __launch_bounds__(256) void k0_zero(float* __restrict__ P) {
    P[blockIdx.x * 256 + threadIdx.x] = 0.f;
}

// split x -> hi(bf16 trunc) + lo(bf16 trunc of exact residual); pack 4 elems
__device__ __forceinline__ void cvt4(float4 v, uint2& hi, uint2& lo) {
    unsigned b0 = __float_as_uint(v.x), b1 = __float_as_uint(v.y);
    unsigned b2 = __float_as_uint(v.z), b3 = __float_as_uint(v.w);
    hi.x = (b0 >> 16) | (b1 & 0xffff0000u);
    hi.y = (b2 >> 16) | (b3 & 0xffff0000u);
    float r0 = v.x - __uint_as_float(b0 & 0xffff0000u);
    float r1 = v.y - __uint_as_float(b1 & 0xffff0000u);
    float r2 = v.z - __uint_as_float(b2 & 0xffff0000u);
    float r3 = v.w - __uint_as_float(b3 & 0xffff0000u);
    lo.x = (__float_as_uint(r0) >> 16) | (__float_as_uint(r1) & 0xffff0000u);
    lo.y = (__float_as_uint(r2) >> 16) | (__float_as_uint(r3) & 0xffff0000u);
}

// MFMA split-K GEMM: part[c][row][col] = sum_{d in chunk c} raw[row][d]*W1[d][col]
// 512 thr = 8 waves in 4(M)x2(N); wave owns 48 rows x 128 cols = 3x8 fragments.
// bf16x3: acc += ah*bh + ah*bl + al*bh  (f32 accumulate in MFMA)
__global__ __launch_bounds__(512, 2)
void k1_mfma(const float* __restrict__ raw, const float* __restrict__ W1,
             const int* __restrict__ vnum, float* __restrict__ outP, int atomicMode)
{
    __shared__ __align__(16) char smem[57344];
    __shared__ char act[NROWS];
    const int t = threadIdx.x;
    const int c = blockIdx.x;
    const int d0 = c * KC;
    if (t < NROWS) act[t] = ((t % NV) < vnum[t / NV]) ? 1 : 0;
    __syncthreads();

    // ---- per-thread staging geometry (constant across steps) ----
    // A: 3 passes, idx = p*512+t : row = idx>>3 (0..191), kq = idx&7 (4 k each)
    int arow[3], akq[3];
    bool aact[3];
    const float* aptr[3];
    int awoff[3];
#pragma unroll
    for (int p = 0; p < 3; ++p) {
        int idx = p * 512 + t;
        int row = idx >> 3, kq = idx & 7;
        arow[p] = row; akq[p] = kq;
        aact[p] = act[row] != 0;
        aptr[p] = raw + (size_t)row * DRAW + d0 + kq * 4;
        int off = ABASE + (row >> 4) * 2048 + (((row & 15) + ((kq >> 1) << 4)) << 4) + ((kq & 1) << 3);
        off ^= ((kq >> 1) & 1) << 6;     // write-side swizzle (matched on reads)
        awoff[p] = off;
    }
    // B: col = t&255, khalf = t>>8; 16 k's (d = d0 + khalf*16 + q) for one col
    const int bcol = t & 255;
    const int bkh = t >> 8;
    const float* bptr = W1 + (size_t)(d0 + bkh * 16) * KOUT + bcol;
    const int bTN = bcol >> 4;
    int bwoff[2];
#pragma unroll
    for (int qh = 0; qh < 2; ++qh) {
        int lane_d = (bcol & 15) + ((bkh * 2 + qh) << 4);
        int off = BBASE + bTN * 2048 + (lane_d << 4);
        off ^= (bTN & 1) << 6;
        bwoff[qh] = off;
    }

    // wave/fragment geometry
    const int lane = t & 63;
    const int wave = t >> 6;
    const int wm = wave >> 1, wn = wave & 1;
    const int aroff = (lane << 4) ^ (((lane >> 4) & 1) << 6);   // A frag read (swizzled)

    f32x4 acc[3][8];
#pragma unroll
    for (int i = 0; i < 3; ++i)
#pragma unroll
        for (int j = 0; j < 8; ++j) acc[i][j] = (f32x4){0.f, 0.f, 0.f, 0.f};

    // ---- prologue: load step-0 regs ----
    float4 Ar[3];
    float Br[16];
#pragma unroll
    for (int p = 0; p < 3; ++p) {
        bool ok = aact[p] && (akq[p] * 4 < KC);
        Ar[p] = ok ? *(const float4*)(aptr[p]) : make_float4(0.f, 0.f, 0.f, 0.f);
    }
#pragma unroll
    for (int q = 0; q < 16; ++q) {
        int dd = bkh * 16 + q;
        Br[q] = (dd < KC) ? bptr[(size_t)q * KOUT] : 0.f;
    }

    for (int s = 0; s < KSTEPS; ++s) {
        __syncthreads();   // prev-step LDS reads done; pending loads drained (used next)
        // ---- convert + LDS write (this step's data) ----
#pragma unroll
        for (int p = 0; p < 3; ++p) {
            uint2 hi, lo; cvt4(Ar[p], hi, lo);
            *(uint2*)(smem + awoff[p]) = hi;
            *(uint2*)(smem + awoff[p] + 1024) = lo;
        }
#pragma unroll
        for (int qh = 0; qh < 2; ++qh) {
            uint2 h0, l0, h1, l1;
            cvt4(make_float4(Br[qh*8+0], Br[qh*8+1], Br[qh*8+2], Br[qh*8+3]), h0, l0);
            cvt4(make_float4(Br[qh*8+4], Br[qh*8+5], Br[qh*8+6], Br[qh*8+7]), h1, l1);
            uint4 hv; hv.x = h0.x; hv.y = h0.y; hv.z = h1.x; hv.w = h1.y;
            uint4 lv; lv.x = l0.x; lv.y = l0.y; lv.z = l1.x; lv.w = l1.y;
            *(uint4*)(smem + bwoff[qh]) = hv;
            *(uint4*)(smem + bwoff[qh] + 1024) = lv;
        }
        // ---- issue next-step global loads (stay in flight through MFMA) ----
        if (s + 1 < KSTEPS) {
            const int koff = (s + 1) * 32;
#pragma unroll
            for (int p = 0; p < 3; ++p) {
                bool ok = aact[p] && (akq[p] * 4 + koff < KC);
                Ar[p] = ok ? *(const float4*)(aptr[p] + koff) : make_float4(0.f, 0.f, 0.f, 0.f);
            }
#pragma unroll
            for (int q = 0; q < 16; ++q) {
                int dd = bkh * 16 + q + koff;
                Br[q] = (dd < KC) ? bptr[(size_t)(koff + q) * KOUT] : 0.f;
            }
        }
        // ---- barrier without vmcnt drain ----
        asm volatile("s_waitcnt lgkmcnt(0)" ::: "memory");
        __builtin_amdgcn_s_barrier();
        // ---- fragment reads + MFMA ----
        short8 ah[3], al[3];
#pragma unroll
        for (int tm = 0; tm < 3; ++tm) {
            int off = ABASE + (wm * 3 + tm) * 2048 + aroff;
            ah[tm] = *(const short8*)(smem + off);
            al[tm] = *(const short8*)(smem + off + 1024);
        }
#pragma unroll
        for (int tn = 0; tn < 8; ++tn) {
            int off = BBASE + (wn * 8 + tn) * 2048 + ((lane << 4) ^ ((tn & 1) << 6));
            short8 bh = *(const short8*)(smem + off);
            short8 bl = *(const short8*)(smem + off + 1024);
#pragma unroll
            for (int tm = 0; tm < 3; ++tm) {
                acc[tm][tn] = __builtin_amdgcn_mfma_f32_16x16x32_bf16(ah[tm], bh, acc[tm][tn], 0, 0, 0);
                acc[tm][tn] = __builtin_amdgcn_mfma_f32_16x16x32_bf16(ah[tm], bl, acc[tm][tn], 0, 0, 0);
                acc[tm][tn] = __builtin_amdgcn_mfma_f32_16x16x32_bf16(al[tm], bh, acc[tm][tn], 0, 0, 0);
            }
        }
    }

    // ---- epilogue: C/D layout col=lane&15, row=(lane>>4)*4+r ----
    const size_t base = (size_t)c * NROWS * KOUT;
#pragma unroll
    for (int tm = 0; tm < 3; ++tm) {
        int row0 = wm * 48 + tm * 16 + ((lane >> 4) << 2);
#pragma unroll
        for (int tn = 0; tn < 8; ++tn) {
            int col = wn * 128 + tn * 16 + (lane & 15);
            f32x4 a = acc[tm][tn];
            if (atomicMode) {
#pragma unroll
                for (int r = 0; r < 4; ++r)
                    atomicAdd(&outP[(size_t)(row0 + r) * KOUT + col], a[r]);
            } else {
                float* dst = outP + base + (size_t)row0 * KOUT + col;
#pragma unroll
                for (int r = 0; r < 4; ++r) dst[(size_t)r * KOUT] = a[r];
            }
        }
    }
}

// Reduce partials + score head: h=relu(P+b1); sraw=relu(h.W2+b2);
// score = sigmoid(tanh(|sraw|))
__global__ __launch_bounds__(256)
void k2_score(const float* __restrict__ part, int nchunk,
              const float* __restrict__ b1, const float* __restrict__ W2,
              const float* __restrict__ b2, float* __restrict__ score)
{
    const int row = blockIdx.x;
    const int t = threadIdx.x;
    float s = 0.f;
    for (int cI = 0; cI < nchunk; ++cI)
        s += part[(size_t)cI * NROWS * KOUT + row * KOUT + t];
    float h = fmaxf(s + b1[t], 0.f);
    float val = h * W2[t];
    for (int o = 32; o > 0; o >>= 1) val += __shfl_down(val, o, 64);
    __shared__ float red[4];
    if ((t & 63) == 0) red[t >> 6] = val;
    __syncthreads();
    if (t == 0) {
        float sm = red[0] + red[1] + red[2] + red[3];
        float sraw = fmaxf(sm + b2[0], 0.f);
        float sc = 1.f / (1.f + expf(-tanhf(fabsf(sraw))));
        score[row] = sc;
    }
}

// Per-sample binning -> per-view fusion coefficient
__global__ __launch_bounds__(64)
void k3_bins(const float* __restrict__ score, const int* __restrict__ vnum,
             float* __restrict__ coeff)
{
    const int n = blockIdx.x;
    const int v = threadIdx.x;
    __shared__ int cnt[NG];
    __shared__ float wsum[NG], wt[NG], wtot;
    if (v < NG) { cnt[v] = 0; wsum[v] = 0.f; }
    __syncthreads();
    const int vn = vnum[n];
    const bool act = (v < NV) && (v < vn);
    float sc = 0.f;
    int b = 0;
    if (act) {
        sc = score[n * NV + v];
        b = (int)floorf(sc * 8.f);
        b = b < 0 ? 0 : (b > 7 ? 7 : b);
        atomicAdd(&cnt[b], 1);
    }
    __syncthreads();
    if (act) atomicAdd(&wsum[b], ceilf(sc * (float)cnt[b]));
    __syncthreads();
    if (v < NG) wt[v] = (cnt[v] > 0) ? wsum[v] / (float)cnt[v] : 0.f;
    __syncthreads();
    if (v == 0) {
        float s = 0.f;
        for (int g = 0; g < NG; ++g) s += wt[g];
        wtot = s;
    }
    __syncthreads();
    if (v < NV)
        coeff[n * NV + v] = act ? wt[b] / ((float)cnt[b] * wtot) : 0.f;
}

__global__ __launch_bounds__(256)
void k4_desc(const float* __restrict__ fv, const float* __restrict__ coeff,
             float* __restrict__ desc)
{
    const int n = blockIdx.y;
    const int d = blockIdx.x * 256 + threadIdx.x;
    float a = 0.f;
#pragma unroll
    for (int v = 0; v < NV; ++v)
        a = fmaf(coeff[n * NV + v], fv[((size_t)n * NV + v) * DFEAT + d], a);
    desc[n * DFEAT + d] = a;
}

__global__ __launch_bounds__(256)
void k5a(const float* __restrict__ desc, const float* __restrict__ Wf1,
         const float* __restrict__ bf1, float* __restrict__ z1)
{
    const int j = blockIdx.x * 256 + threadIdx.x;
    const int n0 = blockIdx.y * 2;
    float a0 = 0.f, a1 = 0.f;
    for (int d = 0; d < DFEAT; ++d) {
        float w = Wf1[d * 512 + j];
        a0 = fmaf(desc[n0 * DFEAT + d], w, a0);
        a1 = fmaf(desc[(n0 + 1) * DFEAT + d], w, a1);
    }
    z1[n0 * 512 + j] = fmaxf(a0 + bf1[j], 0.f);
    z1[(n0 + 1) * 512 + j] = fmaxf(a1 + bf1[j], 0.f);
}

__global__ __launch_bounds__(256)
void k5b(const float* __restrict__ z1, const float* __restrict__ Wf2,
         const float* __restrict__ bf2, float* __restrict__ z2)
{
    const int j = threadIdx.x;
    const int n0 = blockIdx.x * 2;
    float a0 = 0.f, a1 = 0.f;
    for (int d = 0; d < 512; ++d) {
        float w = Wf2[d * 256 + j];
        a0 = fmaf(z1[n0 * 512 + d], w, a0);
        a1 = fmaf(z1[(n0 + 1) * 512 + d], w, a1);
    }
    z2[n0 * 256 + j] = fmaxf(a0 + bf2[j], 0.f);
    z2[(n0 + 1) * 256 + j] = fmaxf(a1 + bf2[j], 0.f);
}

__global__ __launch_bounds__(640)
void k5c(const float* __restrict__ z2, const float* __restrict__ Wl,
         const float* __restrict__ bl, float* __restrict__ out)
{
    const int t = threadIdx.x;
    const int n = t / NCLS;
    const int j = t % NCLS;
    float a = 0.f;
    for (int d = 0; d < 256; ++d)
        a = fmaf(z2[n * 256 + d], Wl[d * NCLS + j], a);
    out[t] = a + bl[j];
}

extern "C" void kernel_launch(void* const* d_in, const int* in_sizes, int n_in,
                              void* d_out, int out_size, void* d_ws, size_t ws_size,
                              hipStream_t stream)
{
    const float* raw  = (const float*)d_in[0];
    const float* fv   = (const float*)d_in[1];
    const int*   vnum = (const int*)d_in[2];
    const float* W1   = (const float*)d_in[3];
    const float* b1   = (const float*)d_in[4];
    const float* W2   = (const float*)d_in[5];
    const float* b2   = (const float*)d_in[6];
    const float* Wf1  = (const float*)d_in[7];
    const float* bf1  = (const float*)d_in[8];
    const float* Wf2  = (const float*)d_in[9];
    const float* bf2  = (const float*)d_in[10];
    const float* Wl   = (const float*)d_in[11];
    const float* bl   = (const float*)d_in[12];
    float* out = (float*)d_out;
    char* ws = (char*)d_ws;
    float* P     = (float*)(ws + WS_P);
    float* score = (float*)(ws + WS_SCORE);
    float* coeff = (float*)(ws + WS_COEFF);
    float* desc  = (float*)(ws + WS_DESC);
    float* z1    = (float*)(ws + WS_Z1);
    float* z2    = (float*)(ws + WS_Z2);
    float* part  = (float*)(ws + WS_PART);

    const bool twophase = (ws_size >= WS_NEED);
    if (twophase) {
        k1_mfma<<<NCHUNK, 512, 0, stream>>>(raw, W1, vnum, part, 0);
        k2_score<<<NROWS, 256, 0, stream>>>(part, NCHUNK, b1, W2, b2, score);
    } else {
        k0_zero<<<NROWS, 256, 0, stream>>>(P);
        k1_mfma<<<NCHUNK, 512, 0, stream>>>(raw, W1, vnum, P, 1);
        k2_score<<<NROWS, 256, 0, stream>>>(P, 1, b1, W2, b2, score);
    }
    k3_bins<<<NB, 64, 0, stream>>>(score, vnum, coeff);
    k4_desc<<<dim3(4, NB), 256, 0, stream>>>(fv, coeff, desc);
    k5a<<<dim3(2, 8), 256, 0, stream>>>(desc, Wf1, bf1, z1);
    k5b<<<8, 256, 0, stream>>>(z1, Wf2, bf2, z2);
    k5c<<<1, 640, 0, stream>>>(z2, Wl, bl, out);
}

// Round 3
// 214.518 us; speedup vs baseline: 3.1062x; 1.1825x over previous
//
#include <hip/hip_runtime.h>
#include <math.h>

// Problem dims (fixed)
#define NB 16
#define NV 12
#define NROWS 192          // NB*NV
#define DRAW 200704
#define KOUT 256
#define DFEAT 1024
#define NG 8
#define NCLS 40

// K1 GEMM decomposition: 512 blocks = 256 K-chunks x 2 col-halves.
// Chunk K = 784 = 24*32 + 16 -> 25 steps of 32 (last step half-masked).
#define NCHUNK 256
#define KC 784
#define KSTEPS 25

// LDS (bytes): A 12 tiles x 2048 (1KB hi + 1KB lo, fragment-linear),
// B 8 tiles x 2048. Total 40960 -> 2 blocks/CU.
#define ABASE 0
#define BBASE 24576

// workspace layout (bytes)
#define WS_COEFF  0                         // [192] f32
#define WS_DESC   1024                      // [16][1024] f32
#define WS_Z1ACC  66560                     // [16][512] f32
#define WS_Z2ACC  99328                     // [16][256] f32  (contig w/ z1acc)
#define WS_P      131072                    // [192][256] f32 (atomic fallback)
#define WS_PART   524288                    // [256][192][256] f32
#define WS_NEED   (WS_PART + (size_t)NCHUNK*NROWS*KOUT*4)

typedef __attribute__((ext_vector_type(8))) short short8;
typedef __attribute__((ext_vector_type(4))) float f32x4;

__global__ __launch_bounds__(256) void k0_zero(float* __restrict__ P) {
    P[blockIdx.x * 256 + threadIdx.x] = 0.f;
}

// split x -> hi(bf16 trunc) + lo(bf16 trunc of exact residual); pack 4 elems
__device__ __forceinline__ void cvt4(float4 v, uint2& hi, uint2& lo) {
    unsigned b0 = __float_as_uint(v.x), b1 = __float_as_uint(v.y);
    unsigned b2 = __float_as_uint(v.z), b3 = __float_as_uint(v.w);
    hi.x = (b0 >> 16) | (b1 & 0xffff0000u);
    hi.y = (b2 >> 16) | (b3 & 0xffff0000u);
    float r0 = v.x - __uint_as_float(b0 & 0xffff0000u);
    float r1 = v.y - __uint_as_float(b1 & 0xffff0000u);
    float r2 = v.z - __uint_as_float(b2 & 0xffff0000u);
    float r3 = v.w - __uint_as_float(b3 & 0xffff0000u);
    lo.x = (__float_as_uint(r0) >> 16) | (__float_as_uint(r1) & 0xffff0000u);
    lo.y = (__float_as_uint(r2) >> 16) | (__float_as_uint(r3) & 0xffff0000u);
}

// issue next-step global loads into named reg buffers (counted-vmcnt prefetch)
#define K1_LOAD(DA, DB, S1)                                                    \
  {                                                                            \
    const int koff = (S1) * 32;                                                \
    _Pragma("unroll") for (int p = 0; p < 3; ++p) {                            \
      bool ok = aact[p] && (akq[p] * 4 + koff < KC);                           \
      DA[p] = ok ? *(const float4*)(aptr[p] + koff)                            \
                 : make_float4(0.f, 0.f, 0.f, 0.f);                            \
    }                                                                          \
    _Pragma("unroll") for (int q = 0; q < 8; ++q) {                            \
      int dd = bkh * 8 + q + koff;                                             \
      DB[q] = (dd < KC) ? bptr[(size_t)(koff + q) * KOUT] : 0.f;               \
    }                                                                          \
  }

// one K-step: top sync (drains prev prefetch exactly at its consume point),
// issue s+1 loads, cvt+stage s, raw lgkm+barrier (NO vmcnt drain -> s+1 loads
// stay in flight through MFMA), fragment reads + 36 MFMAs.
#define K1_STEP(CA, CB, NA, NB_, S, DOLOAD)                                    \
  {                                                                            \
    __syncthreads();                                                           \
    if (DOLOAD) K1_LOAD(NA, NB_, (S) + 1);                                     \
    _Pragma("unroll") for (int p = 0; p < 3; ++p) {                            \
      uint2 hi, lo; cvt4(CA[p], hi, lo);                                       \
      *(uint2*)(smem + awoff[p]) = hi;                                         \
      *(uint2*)(smem + awoff[p] + 1024) = lo;                                  \
    }                                                                          \
    {                                                                          \
      uint2 h0, l0, h1, l1;                                                    \
      cvt4(make_float4(CB[0], CB[1], CB[2], CB[3]), h0, l0);                   \
      cvt4(make_float4(CB[4], CB[5], CB[6], CB[7]), h1, l1);                   \
      uint4 hv; hv.x = h0.x; hv.y = h0.y; hv.z = h1.x; hv.w = h1.y;            \
      uint4 lv; lv.x = l0.x; lv.y = l0.y; lv.z = l1.x; lv.w = l1.y;            \
      *(uint4*)(smem + bwoff) = hv;                                            \
      *(uint4*)(smem + bwoff + 1024) = lv;                                     \
    }                                                                          \
    asm volatile("s_waitcnt lgkmcnt(0)" ::: "memory");                         \
    __builtin_amdgcn_s_barrier();                                              \
    __builtin_amdgcn_sched_barrier(0);                                         \
    short8 ah[3], al[3];                                                       \
    _Pragma("unroll") for (int tm = 0; tm < 3; ++tm) {                         \
      int off = ABASE + (wm * 3 + tm) * 2048 + aroff;                          \
      ah[tm] = *(const short8*)(smem + off);                                   \
      al[tm] = *(const short8*)(smem + off + 1024);                            \
    }                                                                          \
    _Pragma("unroll") for (int tn = 0; tn < 4; ++tn) {                         \
      int off = BBASE + (wn * 4 + tn) * 2048 + ((lane << 4) ^ ((tn & 1) << 6));\
      short8 bh = *(const short8*)(smem + off);                                \
      short8 bl = *(const short8*)(smem + off + 1024);                         \
      _Pragma("unroll") for (int tm = 0; tm < 3; ++tm) {                       \
        acc[tm][tn] = __builtin_amdgcn_mfma_f32_16x16x32_bf16(ah[tm], bh, acc[tm][tn], 0, 0, 0); \
        acc[tm][tn] = __builtin_amdgcn_mfma_f32_16x16x32_bf16(ah[tm], bl, acc[tm][tn], 0, 0, 0); \
        acc[tm][tn] = __builtin_amdgcn_mfma_f32_16x16x32_bf16(al[tm], bh, acc[tm][tn], 0, 0, 0); \
      }                                                                        \
    }                                                                          \
  }

// MFMA split-K/split-N GEMM: block b: chunk c=b>>1, col-half=b&1 (128 cols).
// 512 thr = 8 waves 4(M)x2(N); wave owns 48 rows x 64 cols = 3x4 fragments.
// bf16x3: acc += ah*bh + ah*bl + al*bh (f32 accumulate in MFMA).
__global__ __launch_bounds__(512, 2)
void k1_mfma(const float* __restrict__ raw, const float* __restrict__ W1,
             const int* __restrict__ vnum, float* __restrict__ outP, int atomicMode)
{
    __shared__ __align__(16) char smem[40960];
    __shared__ char act[NROWS];
    const int t = threadIdx.x;
    const int c = blockIdx.x >> 1;
    const int colbase = (blockIdx.x & 1) * 128;
    const int d0 = c * KC;
    if (t < NROWS) act[t] = ((t % NV) < vnum[t / NV]) ? 1 : 0;
    __syncthreads();

    // ---- A staging geometry: 3 passes, idx=p*512+t: row=idx>>3, kq=idx&7 ----
    int akq[3];
    bool aact[3];
    const float* aptr[3];
    int awoff[3];
#pragma unroll
    for (int p = 0; p < 3; ++p) {
        int idx = p * 512 + t;
        int row = idx >> 3, kq = idx & 7;
        akq[p] = kq;
        aact[p] = act[row] != 0;
        aptr[p] = raw + (size_t)row * DRAW + d0 + kq * 4;
        int off = ABASE + (row >> 4) * 2048 + (((row & 15) + ((kq >> 1) << 4)) << 4) + ((kq & 1) << 3);
        off ^= ((kq >> 1) & 1) << 6;
        awoff[p] = off;
    }
    // ---- B staging: col = t&127 (within half), kgroup bkh = t>>7 (8 k each) ----
    const int bcol = t & 127;
    const int bkh = t >> 7;
    const float* bptr = W1 + (size_t)(d0 + bkh * 8) * KOUT + colbase + bcol;
    const int bTN = bcol >> 4;
    int bwoff = BBASE + bTN * 2048 + (((bcol & 15) + (bkh << 4)) << 4);
    bwoff ^= (bTN & 1) << 6;

    // wave/fragment geometry
    const int lane = t & 63;
    const int wave = t >> 6;
    const int wm = wave >> 1, wn = wave & 1;
    const int aroff = (lane << 4) ^ (((lane >> 4) & 1) << 6);

    f32x4 acc[3][4];
#pragma unroll
    for (int i = 0; i < 3; ++i)
#pragma unroll
        for (int j = 0; j < 4; ++j) acc[i][j] = (f32x4){0.f, 0.f, 0.f, 0.f};

    float4 A0[3], A1[3];
    float B0r[8], B1r[8];
    K1_LOAD(A0, B0r, 0);

#pragma unroll 1
    for (int sp = 0; sp < 12; ++sp) {
        K1_STEP(A0, B0r, A1, B1r, 2 * sp, 1);
        K1_STEP(A1, B1r, A0, B0r, 2 * sp + 1, 1);
    }
    K1_STEP(A0, B0r, A1, B1r, 24, 0);

    // ---- epilogue: C/D layout col=lane&15, row=(lane>>4)*4+r ----
    const size_t base = (size_t)c * NROWS * KOUT;
#pragma unroll
    for (int tm = 0; tm < 3; ++tm) {
        int row0 = wm * 48 + tm * 16 + ((lane >> 4) << 2);
#pragma unroll
        for (int tn = 0; tn < 4; ++tn) {
            int col = colbase + wn * 64 + tn * 16 + (lane & 15);
            f32x4 a = acc[tm][tn];
            if (atomicMode) {
#pragma unroll
                for (int r = 0; r < 4; ++r)
                    atomicAdd(&outP[(size_t)(row0 + r) * KOUT + col], a[r]);
            } else {
                float* dst = outP + base + (size_t)row0 * KOUT + col;
#pragma unroll
                for (int r = 0; r < 4; ++r) dst[(size_t)r * KOUT] = a[r];
            }
        }
    }
}

// in-place group reduce: part[g*32][row][col] = sum over 32 chunks
__global__ __launch_bounds__(256)
void k2a(float* __restrict__ part)
{
    const int g = blockIdx.x, row = blockIdx.y, t = threadIdx.x;
    const size_t base = (size_t)g * 32 * NROWS * KOUT + (size_t)row * KOUT + t;
    float s = 0.f;
#pragma unroll
    for (int i = 0; i < 32; ++i) s += part[base + (size_t)i * NROWS * KOUT];
    part[base] = s;
}

// fused: final reduce + score head + binning -> per-view coeff. 1 block/sample.
__global__ __launch_bounds__(256)
void k2s(const float* __restrict__ src, int ngroups, size_t gstride,
         const float* __restrict__ b1, const float* __restrict__ W2,
         const float* __restrict__ b2, const int* __restrict__ vnum,
         float* __restrict__ coeff)
{
    const int n = blockIdx.x, t = threadIdx.x;
    __shared__ float red[4], sc_s[NV], wsum[NG], wt[NG], wtotS;
    __shared__ int cnt[NG];
    const int vn = vnum[n];
    for (int v = 0; v < NV; ++v) {
        float s = 0.f;
        const size_t base = (size_t)(n * NV + v) * KOUT + t;
        for (int g = 0; g < ngroups; ++g) s += src[base + (size_t)g * gstride];
        float h = fmaxf(s + b1[t], 0.f);
        float val = h * W2[t];
        for (int o = 32; o > 0; o >>= 1) val += __shfl_down(val, o, 64);
        if ((t & 63) == 0) red[t >> 6] = val;
        __syncthreads();
        if (t == 0) {
            float sm = red[0] + red[1] + red[2] + red[3];
            float sraw = fmaxf(sm + b2[0], 0.f);
            sc_s[v] = 1.f / (1.f + expf(-tanhf(fabsf(sraw))));
        }
        __syncthreads();
    }
    if (t < NG) { cnt[t] = 0; wsum[t] = 0.f; }
    __syncthreads();
    const bool act = (t < NV) && (t < vn);
    float sc = 0.f; int b = 0;
    if (act) {
        sc = sc_s[t];
        b = (int)floorf(sc * 8.f);
        b = b < 0 ? 0 : (b > 7 ? 7 : b);
        atomicAdd(&cnt[b], 1);
    }
    __syncthreads();
    if (act) atomicAdd(&wsum[b], ceilf(sc * (float)cnt[b]));
    __syncthreads();
    if (t < NG) wt[t] = (cnt[t] > 0) ? wsum[t] / (float)cnt[t] : 0.f;
    __syncthreads();
    if (t == 0) {
        float x = 0.f;
        for (int g = 0; g < NG; ++g) x += wt[g];
        wtotS = x;
    }
    __syncthreads();
    if (t < NV) coeff[n * NV + t] = act ? wt[b] / ((float)cnt[b] * wtotS) : 0.f;
}

// desc[n][d] = sum_v coeff[n][v] * final_views[n][v][d]
__global__ __launch_bounds__(256)
void k4_desc(const float* __restrict__ fv, const float* __restrict__ coeff,
             float* __restrict__ desc)
{
    const int n = blockIdx.y;
    const int d = blockIdx.x * 256 + threadIdx.x;
    float a = 0.f;
#pragma unroll
    for (int v = 0; v < NV; ++v)
        a = fmaf(coeff[n * NV + v], fv[((size_t)n * NV + v) * DFEAT + d], a);
    desc[n * DFEAT + d] = a;
}

// split-K: z1acc[n][j] += sum_{d in kg} desc[n][d]*Wf1[d][j]
__global__ __launch_bounds__(256)
void k5a(const float* __restrict__ desc, const float* __restrict__ Wf1,
         float* __restrict__ z1acc)
{
    const int j = blockIdx.x * 256 + threadIdx.x;   // 0..511
    const int n0 = blockIdx.y * 2;
    const int d0 = blockIdx.z * 256;
    float a0 = 0.f, a1 = 0.f;
    for (int dd = 0; dd < 256; ++dd) {
        int d = d0 + dd;
        float w = Wf1[(size_t)d * 512 + j];
        a0 = fmaf(desc[n0 * DFEAT + d], w, a0);
        a1 = fmaf(desc[(n0 + 1) * DFEAT + d], w, a1);
    }
    atomicAdd(&z1acc[n0 * 512 + j], a0);
    atomicAdd(&z1acc[(n0 + 1) * 512 + j], a1);
}

// split-K: z2acc[n][j] += sum_{d in kg} relu(z1acc[n][d]+bf1[d])*Wf2[d][j]
__global__ __launch_bounds__(256)
void k5b(const float* __restrict__ z1acc, const float* __restrict__ bf1,
         const float* __restrict__ Wf2, float* __restrict__ z2acc)
{
    const int j = threadIdx.x;
    const int n0 = blockIdx.x * 2;
    const int d0 = blockIdx.y * 256;
    float a0 = 0.f, a1 = 0.f;
    for (int dd = 0; dd < 256; ++dd) {
        int d = d0 + dd;
        float w = Wf2[(size_t)d * 256 + j];
        float x0 = fmaxf(z1acc[n0 * 512 + d] + bf1[d], 0.f);
        float x1 = fmaxf(z1acc[(n0 + 1) * 512 + d] + bf1[d], 0.f);
        a0 = fmaf(x0, w, a0);
        a1 = fmaf(x1, w, a1);
    }
    atomicAdd(&z2acc[n0 * 256 + j], a0);
    atomicAdd(&z2acc[(n0 + 1) * 256 + j], a1);
}

// out = relu(z2acc+bf2) @ Wl + bl
__global__ __launch_bounds__(640)
void k5c(const float* __restrict__ z2acc, const float* __restrict__ bf2,
         const float* __restrict__ Wl, const float* __restrict__ bl,
         float* __restrict__ out)
{
    const int t = threadIdx.x;
    const int n = t / NCLS, j = t % NCLS;
    float a = 0.f;
    for (int d = 0; d < 256; ++d)
        a = fmaf(fmaxf(z2acc[n * 256 + d] + bf2[d], 0.f), Wl[d * NCLS + j], a);
    out[t] = a + bl[j];
}

extern "C" void kernel_launch(void* const* d_in, const int* in_sizes, int n_in,
                              void* d_out, int out_size, void* d_ws, size_t ws_size,
                              hipStream_t stream)
{
    const float* raw  = (const float*)d_in[0];
    const float* fv   = (const float*)d_in[1];
    const int*   vnum = (const int*)d_in[2];
    const float* W1   = (const float*)d_in[3];
    const float* b1   = (const float*)d_in[4];
    const float* W2   = (const float*)d_in[5];
    const float* b2   = (const float*)d_in[6];
    const float* Wf1  = (const float*)d_in[7];
    const float* bf1  = (const float*)d_in[8];
    const float* Wf2  = (const float*)d_in[9];
    const float* bf2  = (const float*)d_in[10];
    const float* Wl   = (const float*)d_in[11];
    const float* bl   = (const float*)d_in[12];
    float* out = (float*)d_out;
    char* ws = (char*)d_ws;
    float* coeff = (float*)(ws + WS_COEFF);
    float* desc  = (float*)(ws + WS_DESC);
    float* z1acc = (float*)(ws + WS_Z1ACC);
    float* z2acc = (float*)(ws + WS_Z2ACC);
    float* P     = (float*)(ws + WS_P);
    float* part  = (float*)(ws + WS_PART);

    // zero classifier accumulators (z1acc..z2acc contiguous: 48 KiB = 12288 f32)
    k0_zero<<<48, 256, 0, stream>>>(z1acc);

    const bool twophase = (ws_size >= WS_NEED);
    if (twophase) {
        k1_mfma<<<2 * NCHUNK, 512, 0, stream>>>(raw, W1, vnum, part, 0);
        k2a<<<dim3(8, NROWS), 256, 0, stream>>>(part);
        k2s<<<NB, 256, 0, stream>>>(part, 8, (size_t)32 * NROWS * KOUT,
                                    b1, W2, b2, vnum, coeff);
    } else {
        k0_zero<<<NROWS, 256, 0, stream>>>(P);
        k1_mfma<<<2 * NCHUNK, 512, 0, stream>>>(raw, W1, vnum, P, 1);
        k2s<<<NB, 256, 0, stream>>>(P, 1, 0, b1, W2, b2, vnum, coeff);
    }
    k4_desc<<<dim3(4, NB), 256, 0, stream>>>(fv, coeff, desc);
    k5a<<<dim3(2, 8, 4), 256, 0, stream>>>(desc, Wf1, z1acc);
    k5b<<<dim3(8, 2), 256, 0, stream>>>(z1acc, bf1, Wf2, z2acc);
    k5c<<<1, 640, 0, stream>>>(z2acc, bf2, Wl, bl, out);
}

// Round 4
// 195.741 us; speedup vs baseline: 3.4042x; 1.0959x over previous
//
#include <hip/hip_runtime.h>
#include <math.h>

// Problem dims (fixed)
#define NB 16
#define NV 12
#define NROWS 192          // NB*NV
#define DRAW 200704
#define KOUT 256
#define DFEAT 1024
#define NG 8
#define NCLS 40

// K1 GEMM decomposition: 512 blocks = 256 K-chunks x 2 col-halves.
// Chunk K = 784 = 24*32 + 16 -> 25 steps of 32 (last step half-masked).
#define NCHUNK 256
#define KC 784
#define KSTEPS 25

// LDS (bytes): A 12 tiles x 2048 (1KB hi + 1KB lo, fragment-linear),
// B 8 tiles x 2048. Total 40960 -> 2 blocks/CU.
#define ABASE 0
#define BBASE 24576

// workspace layout (bytes)
#define WS_SCORE  0                         // [192] f32
#define WS_P      4096                      // [192][256] f32 (atomic fallback)
#define WS_PART   524288                    // [256][192][256] f32
#define WS_NEED   (WS_PART + (size_t)NCHUNK*NROWS*KOUT*4)

typedef __attribute__((ext_vector_type(8))) short short8;
typedef __attribute__((ext_vector_type(4))) float f32x4;

__global__ __launch_bounds__(256) void k0_zero(float* __restrict__ P) {
    P[blockIdx.x * 256 + threadIdx.x] = 0.f;
}

// split x -> hi(bf16 trunc) + lo(bf16 trunc of exact residual); pack 4 elems
__device__ __forceinline__ void cvt4(float4 v, uint2& hi, uint2& lo) {
    unsigned b0 = __float_as_uint(v.x), b1 = __float_as_uint(v.y);
    unsigned b2 = __float_as_uint(v.z), b3 = __float_as_uint(v.w);
    hi.x = (b0 >> 16) | (b1 & 0xffff0000u);
    hi.y = (b2 >> 16) | (b3 & 0xffff0000u);
    float r0 = v.x - __uint_as_float(b0 & 0xffff0000u);
    float r1 = v.y - __uint_as_float(b1 & 0xffff0000u);
    float r2 = v.z - __uint_as_float(b2 & 0xffff0000u);
    float r3 = v.w - __uint_as_float(b3 & 0xffff0000u);
    lo.x = (__float_as_uint(r0) >> 16) | (__float_as_uint(r1) & 0xffff0000u);
    lo.y = (__float_as_uint(r2) >> 16) | (__float_as_uint(r3) & 0xffff0000u);
}

// issue step-S1 global loads into named reg buffers
#define K1_LOAD(DA, DB, S1)                                                    \
  {                                                                            \
    const int koff = (S1) * 32;                                                \
    _Pragma("unroll") for (int p = 0; p < 3; ++p) {                            \
      bool ok = aact[p] && (akq[p] * 4 + koff < KC);                           \
      DA[p] = ok ? *(const float4*)(aptr[p] + koff)                            \
                 : make_float4(0.f, 0.f, 0.f, 0.f);                            \
    }                                                                          \
    _Pragma("unroll") for (int q = 0; q < 8; ++q) {                            \
      int dd = bkh * 8 + q + koff;                                             \
      DB[q] = (dd < KC) ? bptr[(size_t)(koff + q) * KOUT] : 0.f;               \
    }                                                                          \
  }

// one K-step. Top barrier is RAW (no vmcnt drain): LDS ordering is guaranteed
// by the mid lgkmcnt(0)+barrier (writes) and MFMA-consumption dataflow (reads);
// vmem loads are thread-private, so the compiler's counted vmcnt at the cvt
// consume point suffices -> memory queue never drains, s+1 loads issue while
// s loads are still arriving.
#define K1_STEP(CA, CB, NA, NB_, S, DOLOAD)                                    \
  {                                                                            \
    __builtin_amdgcn_sched_barrier(0);                                         \
    __builtin_amdgcn_s_barrier();                                              \
    __builtin_amdgcn_sched_barrier(0);                                         \
    if (DOLOAD) K1_LOAD(NA, NB_, (S) + 1);                                     \
    _Pragma("unroll") for (int p = 0; p < 3; ++p) {                            \
      uint2 hi, lo; cvt4(CA[p], hi, lo);                                       \
      *(uint2*)(smem + awoff[p]) = hi;                                         \
      *(uint2*)(smem + awoff[p] + 1024) = lo;                                  \
    }                                                                          \
    {                                                                          \
      uint2 h0, l0, h1, l1;                                                    \
      cvt4(make_float4(CB[0], CB[1], CB[2], CB[3]), h0, l0);                   \
      cvt4(make_float4(CB[4], CB[5], CB[6], CB[7]), h1, l1);                   \
      uint4 hv; hv.x = h0.x; hv.y = h0.y; hv.z = h1.x; hv.w = h1.y;            \
      uint4 lv; lv.x = l0.x; lv.y = l0.y; lv.z = l1.x; lv.w = l1.y;            \
      *(uint4*)(smem + bwoff) = hv;                                            \
      *(uint4*)(smem + bwoff + 1024) = lv;                                     \
    }                                                                          \
    asm volatile("s_waitcnt lgkmcnt(0)" ::: "memory");                         \
    __builtin_amdgcn_s_barrier();                                              \
    __builtin_amdgcn_sched_barrier(0);                                         \
    short8 ah[3], al[3];                                                       \
    _Pragma("unroll") for (int tm = 0; tm < 3; ++tm) {                         \
      int off = ABASE + (wm * 3 + tm) * 2048 + aroff;                          \
      ah[tm] = *(const short8*)(smem + off);                                   \
      al[tm] = *(const short8*)(smem + off + 1024);                            \
    }                                                                          \
    _Pragma("unroll") for (int tn = 0; tn < 4; ++tn) {                         \
      int off = BBASE + (wn * 4 + tn) * 2048 + ((lane << 4) ^ ((tn & 1) << 6));\
      short8 bh = *(const short8*)(smem + off);                                \
      short8 bl = *(const short8*)(smem + off + 1024);                         \
      _Pragma("unroll") for (int tm = 0; tm < 3; ++tm) {                       \
        acc[tm][tn] = __builtin_amdgcn_mfma_f32_16x16x32_bf16(ah[tm], bh, acc[tm][tn], 0, 0, 0); \
        acc[tm][tn] = __builtin_amdgcn_mfma_f32_16x16x32_bf16(ah[tm], bl, acc[tm][tn], 0, 0, 0); \
        acc[tm][tn] = __builtin_amdgcn_mfma_f32_16x16x32_bf16(al[tm], bh, acc[tm][tn], 0, 0, 0); \
      }                                                                        \
    }                                                                          \
  }

// MFMA split-K/split-N GEMM. Co-XCD bid map: both col-halves of a chunk share
// bid%8 (same XCD under round-robin dispatch) -> A-chunk reuse hits that
// XCD's L2 instead of refetching HBM.
// 512 thr = 8 waves 4(M)x2(N); wave owns 48 rows x 64 cols = 3x4 fragments.
// bf16x3: acc += ah*bh + ah*bl + al*bh (f32 accumulate in MFMA).
__global__ __launch_bounds__(512, 4)
void k1_mfma(const float* __restrict__ raw, const float* __restrict__ W1,
             const int* __restrict__ vnum, float* __restrict__ outP, int atomicMode)
{
    __shared__ __align__(16) char smem[40960];
    __shared__ char act[NROWS];
    const int t = threadIdx.x;
    const int g8 = blockIdx.x & 7;
    const int i8 = blockIdx.x >> 3;
    const int c = g8 * 32 + (i8 >> 1);
    const int colbase = (i8 & 1) * 128;
    const int d0 = c * KC;
    if (t < NROWS) act[t] = ((t % NV) < vnum[t / NV]) ? 1 : 0;
    __syncthreads();

    // ---- A staging geometry: 3 passes, idx=p*512+t: row=idx>>3, kq=idx&7 ----
    int akq[3];
    bool aact[3];
    const float* aptr[3];
    int awoff[3];
#pragma unroll
    for (int p = 0; p < 3; ++p) {
        int idx = p * 512 + t;
        int row = idx >> 3, kq = idx & 7;
        akq[p] = kq;
        aact[p] = act[row] != 0;
        aptr[p] = raw + (size_t)row * DRAW + d0 + kq * 4;
        int off = ABASE + (row >> 4) * 2048 + (((row & 15) + ((kq >> 1) << 4)) << 4) + ((kq & 1) << 3);
        off ^= ((kq >> 1) & 1) << 6;
        awoff[p] = off;
    }
    // ---- B staging: col = t&127 (within half), kgroup bkh = t>>7 (8 k each) ----
    const int bcol = t & 127;
    const int bkh = t >> 7;
    const float* bptr = W1 + (size_t)(d0 + bkh * 8) * KOUT + colbase + bcol;
    const int bTN = bcol >> 4;
    int bwoff = BBASE + bTN * 2048 + (((bcol & 15) + (bkh << 4)) << 4);
    bwoff ^= (bTN & 1) << 6;

    // wave/fragment geometry
    const int lane = t & 63;
    const int wave = t >> 6;
    const int wm = wave >> 1, wn = wave & 1;
    const int aroff = (lane << 4) ^ (((lane >> 4) & 1) << 6);

    f32x4 acc[3][4];
#pragma unroll
    for (int i = 0; i < 3; ++i)
#pragma unroll
        for (int j = 0; j < 4; ++j) acc[i][j] = (f32x4){0.f, 0.f, 0.f, 0.f};

    float4 A0[3], A1[3];
    float B0r[8], B1r[8];
    K1_LOAD(A0, B0r, 0);

#pragma unroll 1
    for (int sp = 0; sp < 12; ++sp) {
        K1_STEP(A0, B0r, A1, B1r, 2 * sp, 1);
        K1_STEP(A1, B1r, A0, B0r, 2 * sp + 1, 1);
    }
    K1_STEP(A0, B0r, A1, B1r, 24, 0);

    // ---- epilogue: C/D layout col=lane&15, row=(lane>>4)*4+r ----
    const size_t base = (size_t)c * NROWS * KOUT;
#pragma unroll
    for (int tm = 0; tm < 3; ++tm) {
        int row0 = wm * 48 + tm * 16 + ((lane >> 4) << 2);
#pragma unroll
        for (int tn = 0; tn < 4; ++tn) {
            int col = colbase + wn * 64 + tn * 16 + (lane & 15);
            f32x4 a = acc[tm][tn];
            if (atomicMode) {
#pragma unroll
                for (int r = 0; r < 4; ++r)
                    atomicAdd(&outP[(size_t)(row0 + r) * KOUT + col], a[r]);
            } else {
                float* dst = outP + base + (size_t)row0 * KOUT + col;
#pragma unroll
                for (int r = 0; r < 4; ++r) dst[(size_t)r * KOUT] = a[r];
            }
        }
    }
}

// in-place group reduce: part[g*32][row][col] = sum over 32 chunks
__global__ __launch_bounds__(256)
void k2a(float* __restrict__ part)
{
    const int g = blockIdx.x, row = blockIdx.y, t = threadIdx.x;
    const size_t base = (size_t)g * 32 * NROWS * KOUT + (size_t)row * KOUT + t;
    float s = 0.f;
#pragma unroll
    for (int i = 0; i < 32; ++i) s += part[base + (size_t)i * NROWS * KOUT];
    part[base] = s;
}

// per-row score: final reduce + relu(P+b1).W2 head + sigmoid(tanh(|.|))
__global__ __launch_bounds__(256)
void k2b(const float* __restrict__ src, int ngroups, size_t gstride,
         const float* __restrict__ b1, const float* __restrict__ W2,
         const float* __restrict__ b2, float* __restrict__ score)
{
    const int row = blockIdx.x, t = threadIdx.x;
    float s = 0.f;
    for (int g = 0; g < ngroups; ++g)
        s += src[(size_t)row * KOUT + t + (size_t)g * gstride];
    float h = fmaxf(s + b1[t], 0.f);
    float val = h * W2[t];
    for (int o = 32; o > 0; o >>= 1) val += __shfl_down(val, o, 64);
    __shared__ float red[4];
    if ((t & 63) == 0) red[t >> 6] = val;
    __syncthreads();
    if (t == 0) {
        float sm = red[0] + red[1] + red[2] + red[3];
        float sraw = fmaxf(sm + b2[0], 0.f);
        score[row] = 1.f / (1.f + expf(-tanhf(fabsf(sraw))));
    }
}

// fused tail: binning->coeff->desc->3-layer classifier. One block per sample.
__global__ __launch_bounds__(512)
void k5f(const float* __restrict__ score, const int* __restrict__ vnum,
         const float* __restrict__ fv,
         const float* __restrict__ Wf1, const float* __restrict__ bf1,
         const float* __restrict__ Wf2, const float* __restrict__ bf2,
         const float* __restrict__ Wl,  const float* __restrict__ bl,
         float* __restrict__ out)
{
    const int n = blockIdx.x, t = threadIdx.x;
    __shared__ float coeffL[NV], descL[DFEAT], z1L[512], z2L[256];
    __shared__ float wsum[NG], wt[NG], outred[8][NCLS];
    __shared__ int cnt[NG];
    __shared__ float wtotS;
    // ---- binning -> coeff (threads t<64 act; all hit barriers) ----
    if (t < NG) { cnt[t] = 0; wsum[t] = 0.f; }
    __syncthreads();
    const int vn = vnum[n];
    const bool act = (t < NV) && (t < vn);
    float sc = 0.f; int b = 0;
    if (act) {
        sc = score[n * NV + t];
        b = (int)floorf(sc * 8.f); b = b < 0 ? 0 : (b > 7 ? 7 : b);
        atomicAdd(&cnt[b], 1);
    }
    __syncthreads();
    if (act) atomicAdd(&wsum[b], ceilf(sc * (float)cnt[b]));
    __syncthreads();
    if (t < NG) wt[t] = (cnt[t] > 0) ? wsum[t] / (float)cnt[t] : 0.f;
    __syncthreads();
    if (t == 0) { float x = 0.f; for (int g = 0; g < NG; ++g) x += wt[g]; wtotS = x; }
    __syncthreads();
    if (t < NV) coeffL[t] = act ? wt[b] / ((float)cnt[b] * wtotS) : 0.f;
    __syncthreads();
    // ---- desc = sum_v coeff[v]*fv[n][v][:] ----
#pragma unroll
    for (int p = 0; p < 2; ++p) {
        int d = t + p * 512;
        float a = 0.f;
#pragma unroll
        for (int v = 0; v < NV; ++v)
            a = fmaf(coeffL[v], fv[((size_t)n * NV + v) * DFEAT + d], a);
        descL[d] = a;
    }
    __syncthreads();
    // ---- z1 = relu(desc @ Wf1 + bf1) ----
    {
        float a = 0.f;
#pragma unroll 8
        for (int d = 0; d < DFEAT; ++d)
            a = fmaf(descL[d], Wf1[(size_t)d * 512 + t], a);
        z1L[t] = fmaxf(a + bf1[t], 0.f);
    }
    __syncthreads();
    // ---- z2 = relu(z1 @ Wf2 + bf2) ----
    if (t < 256) {
        float a = 0.f;
#pragma unroll 8
        for (int d = 0; d < 512; ++d)
            a = fmaf(z1L[d], Wf2[(size_t)d * 256 + t], a);
        z2L[t] = fmaxf(a + bf2[t], 0.f);
    }
    __syncthreads();
    // ---- out = z2 @ Wl + bl (8-way d-split + reduce) ----
    if (t < 320) {
        int j = t % NCLS, seg = t / NCLS;
        float a = 0.f;
#pragma unroll
        for (int dd = 0; dd < 32; ++dd) {
            int d = seg * 32 + dd;
            a = fmaf(z2L[d], Wl[d * NCLS + j], a);
        }
        outred[seg][j] = a;
    }
    __syncthreads();
    if (t < NCLS) {
        float a = bl[t];
#pragma unroll
        for (int s8 = 0; s8 < 8; ++s8) a += outred[s8][t];
        out[n * NCLS + t] = a;
    }
}

extern "C" void kernel_launch(void* const* d_in, const int* in_sizes, int n_in,
                              void* d_out, int out_size, void* d_ws, size_t ws_size,
                              hipStream_t stream)
{
    const float* raw  = (const float*)d_in[0];
    const float* fv   = (const float*)d_in[1];
    const int*   vnum = (const int*)d_in[2];
    const float* W1   = (const float*)d_in[3];
    const float* b1   = (const float*)d_in[4];
    const float* W2   = (const float*)d_in[5];
    const float* b2   = (const float*)d_in[6];
    const float* Wf1  = (const float*)d_in[7];
    const float* bf1  = (const float*)d_in[8];
    const float* Wf2  = (const float*)d_in[9];
    const float* bf2  = (const float*)d_in[10];
    const float* Wl   = (const float*)d_in[11];
    const float* bl   = (const float*)d_in[12];
    float* out = (float*)d_out;
    char* ws = (char*)d_ws;
    float* score = (float*)(ws + WS_SCORE);
    float* P     = (float*)(ws + WS_P);
    float* part  = (float*)(ws + WS_PART);

    const bool twophase = (ws_size >= WS_NEED);
    if (twophase) {
        k1_mfma<<<2 * NCHUNK, 512, 0, stream>>>(raw, W1, vnum, part, 0);
        k2a<<<dim3(8, NROWS), 256, 0, stream>>>(part);
        k2b<<<NROWS, 256, 0, stream>>>(part, 8, (size_t)32 * NROWS * KOUT,
                                       b1, W2, b2, score);
    } else {
        k0_zero<<<NROWS, 256, 0, stream>>>(P);
        k1_mfma<<<2 * NCHUNK, 512, 0, stream>>>(raw, W1, vnum, P, 1);
        k2b<<<NROWS, 256, 0, stream>>>(P, 1, 0, b1, W2, b2, score);
    }
    k5f<<<NB, 512, 0, stream>>>(score, vnum, fv, Wf1, bf1, Wf2, bf2, Wl, bl, out);
}